// Round 2
// 299.219 us; speedup vs baseline: 1.0288x; 1.0288x over previous
//
#include <hip/hip_runtime.h>
#include <hip/hip_bf16.h>
#include <stdint.h>

// Problem constants (from reference setup_inputs)
#define NN 128
#define TT 64
#define CC 6625
#define SS 25
#define SE 51          // 2*S+1
#define LPW 26         // blank + 25 labels stored per (n,t)
#define NEGV (-1e30f)

// clang native vector type — required for __builtin_nontemporal_load
// (HIP's float4 is a class type the builtin rejects)
typedef float vf4 __attribute__((ext_vector_type(4)));

// ---------------------------------------------------------------------------
// Kernel 1: per-(n,t) row logsumexp over C=6625 + gather of 26 needed classes.
// Two-phase, register-resident: load ~26 elems/thread into regs (pad NEGV),
// block max-reduce, one exp per element, block sum-reduce.
//
//  - gather loads x[cls] hoisted to phase 0 (overlap with streaming loads)
//  - streaming body loads are nontemporal (217 MB, zero reuse)
//  - lp written TRANSPOSED: lp[(n*26+pos)*64 + t]  -> kernel 2 reads become
//    contiguous float4s instead of 64 scattered 4B loads
//  - block 0 zeroes the output (drops the hipMemsetAsync dispatch)
// ---------------------------------------------------------------------------
__global__ __launch_bounds__(256) void lse_gather_kernel(
    const float* __restrict__ logits,
    const int*   __restrict__ targets,
    float*       __restrict__ lp,
    float*       __restrict__ out,
    int          out_elems)
{
    const int row = blockIdx.x;              // n*T + t
    const int tid = threadIdx.x;
    const float* __restrict__ x = logits + (size_t)row * CC;

    // fold the output zeroing into this kernel (stream order protects kernel 2)
    if (row == 0) {
        for (int i = tid; i < out_elems; i += 256) out[i] = 0.f;
    }

    // rows shift by 4 B each (C odd) — find the 16B-aligned body
    const int mis  = (int)(((uintptr_t)x) & 15u) >> 2;
    const int head = (4 - mis) & 3;                 // 0..3 scalars before body
    const int nvec = (CC - head) >> 2;              // 1655 or 1656 float4s
    const int tail = head + (nvec << 2);            // first scalar after body

    const vf4* __restrict__ xv = reinterpret_cast<const vf4*>(x + head);

    // ---- phase 0a: hoisted gather of the 26 needed classes ----
    const int n = row >> 6;                         // row / TT   (TT == 64)
    const int t = row & 63;                         // row % TT
    float g = 0.f;
    if (tid < LPW) {
        const int cls = (tid == 0) ? 0 : targets[n * SS + tid - 1];
        g = x[cls];
    }

    // ---- phase 0b: stream everything into registers (pad with NEGV) ----
    vf4 v[7];
#pragma unroll
    for (int k = 0; k < 7; ++k) {
        const int i = tid + (k << 8);
        if (i < nvec) v[k] = __builtin_nontemporal_load(&xv[i]);
        else          v[k] = (vf4){NEGV, NEGV, NEGV, NEGV};
    }
    const float e0 = (tid < head)       ? x[tid]        : NEGV;  // head scalars
    const float e1 = (tail + tid < CC)  ? x[tail + tid] : NEGV;  // tail scalars

    // ---- phase 1: block max ----
    float m = fmaxf(e0, e1);
#pragma unroll
    for (int k = 0; k < 7; ++k) {
        m = fmaxf(m, fmaxf(fmaxf(v[k].x, v[k].y), fmaxf(v[k].z, v[k].w)));
    }
#pragma unroll
    for (int off = 1; off < 64; off <<= 1)
        m = fmaxf(m, __shfl_xor(m, off, 64));

    __shared__ float sm[4];
    __shared__ float ssv[4];
    const int wid = tid >> 6;
    if ((tid & 63) == 0) sm[wid] = m;
    __syncthreads();
    const float M = fmaxf(fmaxf(sm[0], sm[1]), fmaxf(sm[2], sm[3]));

    // ---- phase 2: block sum of exp(v - M) (padded slots contribute 0) ----
    float s = __expf(e0 - M) + __expf(e1 - M);
#pragma unroll
    for (int k = 0; k < 7; ++k) {
        s += __expf(v[k].x - M) + __expf(v[k].y - M) +
             __expf(v[k].z - M) + __expf(v[k].w - M);
    }
#pragma unroll
    for (int off = 1; off < 64; off <<= 1)
        s += __shfl_xor(s, off, 64);
    if ((tid & 63) == 0) ssv[wid] = s;
    __syncthreads();
    const float S   = ssv[0] + ssv[1] + ssv[2] + ssv[3];
    const float lse = M + __logf(S);

    // ---- write the gathered log-probs, transposed: [n][pos][t] ----
    if (tid < LPW) {
        lp[((size_t)(n * LPW + tid)) * TT + t] = g - lse;
    }
}

// ---------------------------------------------------------------------------
// Kernel 2: CTC alpha recursion (one wave per sample, lane = state) + focal
// weighting + atomic mean into d_out. lp is [n][pos][t] so each lane's
// preload is 16 contiguous float4 loads (256B-aligned) instead of 64
// scattered 4B loads.
// ---------------------------------------------------------------------------
__global__ __launch_bounds__(64) void ctc_alpha_kernel(
    const float* __restrict__ lp,
    const int*   __restrict__ targets,
    const int*   __restrict__ target_length,
    float*       __restrict__ out)
{
    const int n = blockIdx.x;
    const int s = threadIdx.x;                 // lane = extended-state index
    const bool active = (s < SE);

    // slot in the 26-wide lp row: even state -> blank(0), odd -> 1 + s/2
    const int pos = (s & 1) ? (1 + (s >> 1)) : 0;

    bool can_skip = false;
    if (active && (s & 1)) {
        if (s == 1) can_skip = true;
        else {
            const int lab  = targets[n * SS + (s >> 1)];
            const int lab2 = targets[n * SS + (s >> 1) - 1];
            can_skip = (lab != lab2);
        }
    }

    // preload all T log-probs for this lane's state — contiguous, vectorized
    float lpt[TT];
    if (active) {
        const vf4* __restrict__ pv =
            reinterpret_cast<const vf4*>(lp + ((size_t)(n * LPW + pos)) * TT);
#pragma unroll
        for (int k = 0; k < 16; ++k) {
            const vf4 v4 = pv[k];
            lpt[4 * k + 0] = v4.x;
            lpt[4 * k + 1] = v4.y;
            lpt[4 * k + 2] = v4.z;
            lpt[4 * k + 3] = v4.w;
        }
    } else {
#pragma unroll
        for (int t = 0; t < TT; ++t) lpt[t] = NEGV;
    }

    float alpha = (s < 2) ? lpt[0] : NEGV;

#pragma unroll
    for (int t = 1; t < TT; ++t) {
        const float a1 = alpha;
        float a2 = __shfl_up(alpha, 1, 64);
        if (s == 0) a2 = NEGV;
        float a3 = __shfl_up(alpha, 2, 64);
        if (s < 2 || !can_skip) a3 = NEGV;
        const float mx  = fmaxf(a1, fmaxf(a2, a3));
        const float sum = __expf(a1 - mx) + __expf(a2 - mx) + __expf(a3 - mx);
        alpha = active ? (mx + __logf(sum) + lpt[t]) : NEGV;
    }

    int L = target_length[n];
    L = (L < 1) ? 1 : ((L > SS) ? SS : L);
    const float aL1 = __shfl(alpha, 2 * L - 1, 64);
    const float aL2 = __shfl(alpha, 2 * L,     64);
    if (s == 0) {
        const float mx = fmaxf(aL1, aL2);
        const float ll = mx + __logf(__expf(aL1 - mx) + __expf(aL2 - mx));
        const float loss = -ll;
        const float w = 1.f - __expf(-loss);   // focal, GAMMA=2, ALPHA=1
        atomicAdd(out, loss * w * w * (1.0f / NN));
    }
}

// ---------------------------------------------------------------------------
extern "C" void kernel_launch(void* const* d_in, const int* in_sizes, int n_in,
                              void* d_out, int out_size, void* d_ws, size_t ws_size,
                              hipStream_t stream)
{
    const float* logits  = (const float*)d_in[0];   // [N,T,C] f32
    const int*   targets = (const int*)  d_in[1];   // [N,S]   i32
    const int*   tlen    = (const int*)  d_in[2];   // [N]     i32
    float*       out     = (float*)d_out;           // scalar

    float* lp = (float*)d_ws;                       // N*26*T floats (852 KB)

    lse_gather_kernel<<<NN * TT, 256, 0, stream>>>(logits, targets, lp, out, out_size);
    ctc_alpha_kernel<<<NN, 64, 0, stream>>>(lp, targets, tlen, out);
}